// Round 10
// baseline (890.719 us; speedup 1.0000x reference)
//
#include <hip/hip_runtime.h>
#include <math.h>

#define LYRS 6
#define BATCH 16
#define DIM 1024
#define NH 16
#define HDIM 64
#define FFNDIM 4096
#define VOCAB 32000
#define NCACHE 512
#define SRCLEN 512
#define SCALE 0.125f
#define EMB_SCALE 32.0f
#define BD (BATCH * DIM)
#define BF (BATCH * FFNDIM)
#define BV (BATCH * VOCAB)

__device__ __forceinline__ float wave_reduce_sum(float v){
#pragma unroll
  for (int off = 32; off; off >>= 1) v += __shfl_xor(v, off, 64);
  return v;
}
__device__ __forceinline__ float wave_reduce_max(float v){
#pragma unroll
  for (int off = 32; off; off >>= 1) v = fmaxf(v, __shfl_xor(v, off, 64));
  return v;
}
__device__ __forceinline__ float4 silu4(float4 v){
  v.x = v.x / (1.f + __expf(-v.x));
  v.y = v.y / (1.f + __expf(-v.y));
  v.z = v.z / (1.f + __expf(-v.z));
  v.w = v.w / (1.f + __expf(-v.w));
  return v;
}

// h3[b][d] = decoder_embed[b][d]*sqrt(D) + pe[cache_len][d]
__global__ __launch_bounds__(256) void k_embed(const float* __restrict__ de,
                                               const float* __restrict__ pe,
                                               const int* __restrict__ cl,
                                               float* __restrict__ h){
  int b = blockIdx.x, t = threadIdx.x;
  int c = cl[0];
  const float4* d4 = (const float4*)(de + (size_t)b * DIM);
  const float4* p4 = (const float4*)(pe + (size_t)c * DIM);
  float4* h4 = (float4*)(h + (size_t)b * DIM);
  float4 a = d4[t], p = p4[t];
  float4 o;
  o.x = a.x * EMB_SCALE + p.x; o.y = a.y * EMB_SCALE + p.y;
  o.z = a.z * EMB_SCALE + p.z; o.w = a.w * EMB_SCALE + p.w;
  h4[t] = o;
}

// ---------------------------------------------------------------------------
// Staging A: plain (optional NZ partial-slab fold + k-bias + SiLU).
// ---------------------------------------------------------------------------
template<int KPB, int NZ, bool SILU>
__device__ __forceinline__ void plain_stage(float (*As)[KPB],
    const float* __restrict__ Asrc, int a_rs, int pz,
    const float* __restrict__ abias, int k0){
  const int tid = threadIdx.x;
  const int m = tid >> 4, q0 = (tid & 15) * 4;
#pragma unroll
  for (int qq = 0; qq < KPB / 64; ++qq){
    const int q = q0 + qq * 64;
    const int gk = k0 + q;
    float4 v;
    if (NZ == 0){
      v = *(const float4*)(Asrc + (size_t)m * a_rs + gk);
    } else {
      if (abias) v = *(const float4*)(abias + gk);
      else { v.x = 0.f; v.y = 0.f; v.z = 0.f; v.w = 0.f; }
#pragma unroll
      for (int z = 0; z < NZ; ++z){
        float4 pv = *(const float4*)(Asrc + (size_t)z * pz + (size_t)m * a_rs + gk);
        v.x += pv.x; v.y += pv.y; v.z += pv.z; v.w += pv.w;
      }
    }
    if (SILU) v = silu4(v);
    *(float4*)(&As[m][q]) = v;
  }
  __syncthreads();
}

// ---------------------------------------------------------------------------
// Staging A with FUSED LayerNorm: x = res + acc + obias (full row stats,
// redundant per block), stage ln(x) slice; blockIdx-designated writer blocks
// also materialize ln(x) into hout for use as the next residual.
// ---------------------------------------------------------------------------
template<int KPB>
__device__ __forceinline__ void ln_stage(float (*As)[KPB],
    const float* __restrict__ res, const float* __restrict__ acc,
    const float* __restrict__ obias, const float* __restrict__ lnw,
    const float* __restrict__ lnb, int k0, float* __restrict__ hout){
  const int tid = threadIdx.x;
  const int m = tid >> 4, t = tid & 15;
  const float* rr = res + (size_t)m * DIM;
  const float* ar = acc + (size_t)m * DIM;
  float s = 0.f, sq = 0.f;
#pragma unroll
  for (int c = 0; c < 16; ++c){
    const int k = t * 4 + c * 64;
    float4 rv = *(const float4*)(rr + k);
    float4 av = *(const float4*)(ar + k);
    float4 ob = *(const float4*)(obias + k);
    float x0 = rv.x + av.x + ob.x, x1 = rv.y + av.y + ob.y;
    float x2 = rv.z + av.z + ob.z, x3 = rv.w + av.w + ob.w;
    s += x0 + x1 + x2 + x3;
    sq += x0 * x0 + x1 * x1 + x2 * x2 + x3 * x3;
  }
#pragma unroll
  for (int o = 1; o <= 8; o <<= 1){
    s += __shfl_xor(s, o, 64); sq += __shfl_xor(sq, o, 64);
  }
  const float mean = s * (1.f / DIM);
  const float rstd = rsqrtf(sq * (1.f / DIM) - mean * mean + 1e-5f);
#pragma unroll
  for (int qq = 0; qq < KPB / 64; ++qq){
    const int q = t * 4 + qq * 64;
    const int k = k0 + q;
    float4 rv = *(const float4*)(rr + k);
    float4 av = *(const float4*)(ar + k);
    float4 ob = *(const float4*)(obias + k);
    float4 wv = *(const float4*)(lnw + k);
    float4 bv = *(const float4*)(lnb + k);
    float4 o4;
    o4.x = (rv.x + av.x + ob.x - mean) * rstd * wv.x + bv.x;
    o4.y = (rv.y + av.y + ob.y - mean) * rstd * wv.y + bv.y;
    o4.z = (rv.z + av.z + ob.z - mean) * rstd * wv.z + bv.z;
    o4.w = (rv.w + av.w + ob.w - mean) * rstd * wv.w + bv.w;
    *(float4*)(&As[m][q]) = o4;
    if (hout) *(float4*)(hout + (size_t)m * DIM + k) = o4;
  }
  __syncthreads();
}

// ---------------------------------------------------------------------------
// GEMV W-stream loop (double-buffered); output slab store or atomicAdd.
// ---------------------------------------------------------------------------
template<int KPB, bool ATOMIC>
__device__ __forceinline__ void gemv_w_loop(float (*As)[KPB],
    const float* __restrict__ W, int w_rs, float* __restrict__ Cz,
    int c_rs, int n0, int k0){
  const int tid = threadIdx.x, lane = tid & 63;
  const int m0 = (tid >> 6) * 4;
  const float* Wrow = W + (size_t)(n0 + lane) * w_rs + k0;
  float acc0 = 0.f, acc1 = 0.f, acc2 = 0.f, acc3 = 0.f;
  constexpr int CHUNKS = KPB / 64;
  float4 wb[2][16];
#pragma unroll
  for (int c = 0; c < 16; ++c) wb[0][c] = *(const float4*)(Wrow + c * 4);
#pragma unroll
  for (int ch = 0; ch < CHUNKS; ++ch){
    const int cur = ch & 1;
    if (ch + 1 < CHUNKS){
#pragma unroll
      for (int c = 0; c < 16; ++c)
        wb[cur ^ 1][c] = *(const float4*)(Wrow + (ch + 1) * 64 + c * 4);
    }
#pragma unroll
    for (int c = 0; c < 16; ++c){
      float4 wv = wb[cur][c];
      const int q = ch * 64 + c * 4;
      float4 a0 = *(const float4*)(&As[m0 + 0][q]);
      float4 a1 = *(const float4*)(&As[m0 + 1][q]);
      float4 a2 = *(const float4*)(&As[m0 + 2][q]);
      float4 a3 = *(const float4*)(&As[m0 + 3][q]);
      acc0 = fmaf(wv.x, a0.x, acc0); acc0 = fmaf(wv.y, a0.y, acc0);
      acc0 = fmaf(wv.z, a0.z, acc0); acc0 = fmaf(wv.w, a0.w, acc0);
      acc1 = fmaf(wv.x, a1.x, acc1); acc1 = fmaf(wv.y, a1.y, acc1);
      acc1 = fmaf(wv.z, a1.z, acc1); acc1 = fmaf(wv.w, a1.w, acc1);
      acc2 = fmaf(wv.x, a2.x, acc2); acc2 = fmaf(wv.y, a2.y, acc2);
      acc2 = fmaf(wv.z, a2.z, acc2); acc2 = fmaf(wv.w, a2.w, acc2);
      acc3 = fmaf(wv.x, a3.x, acc3); acc3 = fmaf(wv.y, a3.y, acc3);
      acc3 = fmaf(wv.z, a3.z, acc3); acc3 = fmaf(wv.w, a3.w, acc3);
    }
  }
  if (ATOMIC){
    atomicAdd(&Cz[(size_t)(m0 + 0) * c_rs + n0 + lane], acc0);
    atomicAdd(&Cz[(size_t)(m0 + 1) * c_rs + n0 + lane], acc1);
    atomicAdd(&Cz[(size_t)(m0 + 2) * c_rs + n0 + lane], acc2);
    atomicAdd(&Cz[(size_t)(m0 + 3) * c_rs + n0 + lane], acc3);
  } else {
    Cz[(size_t)(m0 + 0) * c_rs + n0 + lane] = acc0;
    Cz[(size_t)(m0 + 1) * c_rs + n0 + lane] = acc1;
    Cz[(size_t)(m0 + 2) * c_rs + n0 + lane] = acc2;
    Cz[(size_t)(m0 + 3) * c_rs + n0 + lane] = acc3;
  }
}

template<int KPB, int NZ, bool SILU, bool ATOMIC>
__global__ __launch_bounds__(256) void k_gemv_ms(
    const float* __restrict__ A, int a_rs, int a_bs, int pz,
    const float* __restrict__ abias,
    const float* __restrict__ W, int w_rs, int w_bs,
    float* __restrict__ C, int c_rs, int c_bs, int c_zs){
  __shared__ float As[16][KPB];
  const int bb = blockIdx.y;
  plain_stage<KPB, NZ, SILU>(As, A + (size_t)bb * a_bs, a_rs, pz, abias,
                             blockIdx.z * KPB);
  gemv_w_loop<KPB, ATOMIC>(As, W + (size_t)bb * w_bs, w_rs,
      C + (size_t)blockIdx.z * c_zs + (size_t)bb * c_bs, c_rs,
      blockIdx.x * 64, blockIdx.z * KPB);
}

// layer-0 QKV (no LN fusion): y selects weight matrix, z=4 slabs
template<int KPB>
__global__ __launch_bounds__(256) void k_gemv_ms3(
    const float* __restrict__ A, const float* __restrict__ W0,
    const float* __restrict__ W1, const float* __restrict__ W2,
    float* __restrict__ C){
  __shared__ float As[16][KPB];
  const int y = blockIdx.y;
  const float* W = (y == 0) ? W0 : ((y == 1) ? W1 : W2);
  plain_stage<KPB, 0, false>(As, A, DIM, 0, nullptr, blockIdx.z * KPB);
  gemv_w_loop<KPB, false>(As, W, DIM,
      C + ((size_t)y * 4 + blockIdx.z) * BD, DIM,
      blockIdx.x * 64, blockIdx.z * KPB);
}

// GEMV with fused input LayerNorm (res + acc + obias), slab output.
template<int KPB>
__global__ __launch_bounds__(256) void k_gemv_ln(
    const float* __restrict__ res, const float* __restrict__ acc,
    const float* __restrict__ obias, const float* __restrict__ lnw,
    const float* __restrict__ lnb, const float* __restrict__ W,
    float* __restrict__ hout, float* __restrict__ C, int c_rs, int c_zs){
  __shared__ float As[16][KPB];
  float* hw = (blockIdx.x == 0) ? hout : nullptr;
  ln_stage<KPB>(As, res, acc, obias, lnw, lnb, blockIdx.z * KPB, hw);
  gemv_w_loop<KPB, false>(As, W, DIM, C + (size_t)blockIdx.z * c_zs, c_rs,
      blockIdx.x * 64, blockIdx.z * KPB);
}

// QKV with fused ln3 of previous layer: y selects weight matrix
template<int KPB>
__global__ __launch_bounds__(256) void k_gemv_ln3(
    const float* __restrict__ res, const float* __restrict__ acc,
    const float* __restrict__ obias, const float* __restrict__ lnw,
    const float* __restrict__ lnb,
    const float* __restrict__ W0, const float* __restrict__ W1,
    const float* __restrict__ W2,
    float* __restrict__ hout, float* __restrict__ C){
  __shared__ float As[16][KPB];
  const int y = blockIdx.y;
  const float* W = (y == 0) ? W0 : ((y == 1) ? W1 : W2);
  float* hw = (blockIdx.x == 0 && y == 0) ? hout : nullptr;
  ln_stage<KPB>(As, res, acc, obias, lnw, lnb, blockIdx.z * KPB, hw);
  gemv_w_loop<KPB, false>(As, W, DIM,
      C + ((size_t)y * 4 + blockIdx.z) * BD, DIM,
      blockIdx.x * 64, blockIdx.z * KPB);
}

// lm_head partial combine: out[i] = P[0][i] + P[1][i]
__global__ __launch_bounds__(256) void k_fin2(const float* __restrict__ P,
                                              float* __restrict__ out){
  int i = blockIdx.x * 256 + threadIdx.x;
  out[i] = P[i] + P[(size_t)BV + i];
}

// Self-attention per (b,h). Folds the 4 QKV k-split partials (+bias),
// writes new k/v to d_out, attends over 513 keys. Also zero-inits the
// three atomic accumulators (A_o/A_co/A_f2, 48K floats) for this layer.
__global__ __launch_bounds__(512) void k_self_attn(
    const float* __restrict__ Pqkv, const float* __restrict__ qb_,
    const float* __restrict__ kb_, const float* __restrict__ vb_,
    const float* __restrict__ pk, const float* __restrict__ pv,
    float* __restrict__ satt, float* __restrict__ out_k,
    float* __restrict__ out_v, float* __restrict__ azero){
  __shared__ float qs[64], ks[64], vs[64];
  __shared__ float sc[513];
  __shared__ float red1[8], red2[8];
  __shared__ float o8[8][64];
  const int bh = blockIdx.x, b = bh >> 4, h = bh & 15;
  const int tid = threadIdx.x, w = tid >> 6, lane = tid & 63;
  const int hd = h * HDIM + lane;
  if (tid < 48){
    float4 z4; z4.x = 0.f; z4.y = 0.f; z4.z = 0.f; z4.w = 0.f;
    ((float4*)azero)[(size_t)bh * 48 + tid] = z4;
  }
  if (w < 3){
    const float* Pz = Pqkv + (size_t)w * (4 * BD);
    const float* bias = (w == 0) ? qb_ : ((w == 1) ? kb_ : vb_);
    float v = bias[hd];
#pragma unroll
    for (int z = 0; z < 4; ++z)
      v += Pz[(size_t)z * BD + b * DIM + hd];
    if (w == 0) qs[lane] = v * SCALE;
    else if (w == 1){ ks[lane] = v; out_k[b * DIM + hd] = v; }
    else { vs[lane] = v; out_v[b * DIM + hd] = v; }
  }
  __syncthreads();
  const int jj = lane >> 4, c = lane & 15;
  float4 q4 = *(const float4*)(&qs[c * 4]);
  const float* kbase = pk + (size_t)b * NCACHE * DIM + h * HDIM + c * 4;
  {
    float4 nk = *(const float4*)(kbase + (size_t)(w * 4 + jj) * DIM);
    for (int it = 0; it < 16; ++it){
      int j = it * 32 + w * 4 + jj;
      float4 K4 = nk;
      if (it < 15) nk = *(const float4*)(kbase + (size_t)(j + 32) * DIM);
      float r = q4.x * K4.x;
      r = fmaf(q4.y, K4.y, r); r = fmaf(q4.z, K4.z, r); r = fmaf(q4.w, K4.w, r);
      r += __shfl_xor(r, 1, 64); r += __shfl_xor(r, 2, 64);
      r += __shfl_xor(r, 4, 64); r += __shfl_xor(r, 8, 64);
      if (c == 0) sc[j] = r;
    }
  }
  if (w == 0 && lane < 16){
    float4 k4 = *(const float4*)(&ks[lane * 4]);
    float r = q4.x * k4.x;
    r = fmaf(q4.y, k4.y, r); r = fmaf(q4.z, k4.z, r); r = fmaf(q4.w, k4.w, r);
    r += __shfl_xor(r, 1, 64); r += __shfl_xor(r, 2, 64);
    r += __shfl_xor(r, 4, 64); r += __shfl_xor(r, 8, 64);
    if (lane == 0) sc[512] = r;
  }
  __syncthreads();
  float lm = -1e30f;
  for (int j2 = tid; j2 < 513; j2 += 512) lm = fmaxf(lm, sc[j2]);
  lm = wave_reduce_max(lm);
  if (lane == 0) red1[w] = lm;
  __syncthreads();
  float bm = red1[0];
#pragma unroll
  for (int ww = 1; ww < 8; ++ww) bm = fmaxf(bm, red1[ww]);
  float ls = 0.f;
  for (int j2 = tid; j2 < 513; j2 += 512){
    float e = __expf(sc[j2] - bm);
    sc[j2] = e;
    ls += e;
  }
  ls = wave_reduce_sum(ls);
  if (lane == 0) red2[w] = ls;
  __syncthreads();
  float tot = 0.f;
#pragma unroll
  for (int ww = 0; ww < 8; ++ww) tot += red2[ww];
  float inv = 1.f / tot;
  const float* vbase = pv + (size_t)b * NCACHE * DIM + h * HDIM + c * 4;
  float4 acc; acc.x = 0.f; acc.y = 0.f; acc.z = 0.f; acc.w = 0.f;
  {
    float4 nv = *(const float4*)(vbase + (size_t)(w * 4 + jj) * DIM);
    for (int it = 0; it < 16; ++it){
      int j = it * 32 + w * 4 + jj;
      float4 V4 = nv;
      if (it < 15) nv = *(const float4*)(vbase + (size_t)(j + 32) * DIM);
      float pj = sc[j];
      acc.x = fmaf(pj, V4.x, acc.x); acc.y = fmaf(pj, V4.y, acc.y);
      acc.z = fmaf(pj, V4.z, acc.z); acc.w = fmaf(pj, V4.w, acc.w);
    }
  }
  if (w == 0 && lane < 16){
    float p512 = sc[512];
    float4 v4 = *(const float4*)(&vs[lane * 4]);
    acc.x = fmaf(p512, v4.x, acc.x); acc.y = fmaf(p512, v4.y, acc.y);
    acc.z = fmaf(p512, v4.z, acc.z); acc.w = fmaf(p512, v4.w, acc.w);
  }
  acc.x += __shfl_xor(acc.x, 16, 64); acc.x += __shfl_xor(acc.x, 32, 64);
  acc.y += __shfl_xor(acc.y, 16, 64); acc.y += __shfl_xor(acc.y, 32, 64);
  acc.z += __shfl_xor(acc.z, 16, 64); acc.z += __shfl_xor(acc.z, 32, 64);
  acc.w += __shfl_xor(acc.w, 16, 64); acc.w += __shfl_xor(acc.w, 32, 64);
  if (lane < 16){
    o8[w][lane * 4 + 0] = acc.x; o8[w][lane * 4 + 1] = acc.y;
    o8[w][lane * 4 + 2] = acc.z; o8[w][lane * 4 + 3] = acc.w;
  }
  __syncthreads();
  if (tid < 64){
    float s2 = 0.f;
#pragma unroll
    for (int ww = 0; ww < 8; ++ww) s2 += o8[ww][tid];
    satt[b * DIM + h * HDIM + tid] = s2 * inv;
  }
}

// g[b][h][c] = sum_d qv[b][hd] * kw[hd][c], qv = (sum8 Pcq + caqb)*SCALE
__global__ __launch_bounds__(256) void k_gmat2(
    const float* __restrict__ Pcq, const float* __restrict__ caqb,
    const float* __restrict__ kw, float* __restrict__ g){
  __shared__ float qsT[64][16];   // [d][b]
  __shared__ float Ps[4][16][64];
  const int h = blockIdx.y, c0 = blockIdx.x * 64;
  const int tid = threadIdx.x, lane = tid & 63, wave = tid >> 6;
  {
    const int b = tid >> 4, q0 = (tid & 15) * 4;
    float4 v = *(const float4*)(caqb + h * HDIM + q0);
#pragma unroll
    for (int z = 0; z < 8; ++z){
      float4 pv = *(const float4*)(Pcq + (size_t)z * BD +
                                   (size_t)b * DIM + h * HDIM + q0);
      v.x += pv.x; v.y += pv.y; v.z += pv.z; v.w += pv.w;
    }
    qsT[q0 + 0][b] = v.x * SCALE; qsT[q0 + 1][b] = v.y * SCALE;
    qsT[q0 + 2][b] = v.z * SCALE; qsT[q0 + 3][b] = v.w * SCALE;
  }
  __syncthreads();
  float wv[16];
#pragma unroll
  for (int dd = 0; dd < 16; ++dd)
    wv[dd] = kw[(size_t)(h * HDIM + wave * 16 + dd) * DIM + c0 + lane];
  float acc[16];
#pragma unroll
  for (int m = 0; m < 16; ++m) acc[m] = 0.f;
#pragma unroll
  for (int dd = 0; dd < 16; ++dd){
    const int d = wave * 16 + dd;
    float4 a0 = *(const float4*)(&qsT[d][0]);
    float4 a1 = *(const float4*)(&qsT[d][4]);
    float4 a2 = *(const float4*)(&qsT[d][8]);
    float4 a3 = *(const float4*)(&qsT[d][12]);
    float wd = wv[dd];
    acc[0] = fmaf(wd, a0.x, acc[0]);  acc[1] = fmaf(wd, a0.y, acc[1]);
    acc[2] = fmaf(wd, a0.z, acc[2]);  acc[3] = fmaf(wd, a0.w, acc[3]);
    acc[4] = fmaf(wd, a1.x, acc[4]);  acc[5] = fmaf(wd, a1.y, acc[5]);
    acc[6] = fmaf(wd, a1.z, acc[6]);  acc[7] = fmaf(wd, a1.w, acc[7]);
    acc[8] = fmaf(wd, a2.x, acc[8]);  acc[9] = fmaf(wd, a2.y, acc[9]);
    acc[10] = fmaf(wd, a2.z, acc[10]); acc[11] = fmaf(wd, a2.w, acc[11]);
    acc[12] = fmaf(wd, a3.x, acc[12]); acc[13] = fmaf(wd, a3.y, acc[13]);
    acc[14] = fmaf(wd, a3.z, acc[14]); acc[15] = fmaf(wd, a3.w, acc[15]);
  }
#pragma unroll
  for (int m = 0; m < 16; ++m) Ps[wave][m][lane] = acc[m];
  __syncthreads();
  const int nl = tid & 63, mg = (tid >> 6) * 4;
#pragma unroll
  for (int mm = 0; mm < 4; ++mm){
    int m = mg + mm;
    float r = Ps[0][m][nl] + Ps[1][m][nl] + Ps[2][m][nl] + Ps[3][m][nl];
    g[((size_t)m * NH + h) * DIM + c0 + nl] = r;
  }
}

// ctx with INLINE softmax over sum of 2 score slabs; then ctx = p . enc
__global__ __launch_bounds__(256) void k_ctx_sm(
    const float* __restrict__ s2b, const float* __restrict__ enc,
    float* __restrict__ ctx){
  __shared__ float pT[SRCLEN][16];
  __shared__ float Ps[4][16][64];
  const int b = blockIdx.y, c0 = blockIdx.x * 64;
  const int tid = threadIdx.x, lane = tid & 63, wave = tid >> 6;
  {
    const int h = tid >> 4, jp = (tid & 15) * 4;
    const size_t row = ((size_t)b * NH + h) * SRCLEN;
    float4 val[8];
    float vmax = -1e30f;
#pragma unroll
    for (int t = 0; t < 8; ++t){
      const int j = jp + t * 64;
      float4 v = *(const float4*)(s2b + row + j);
      float4 v2 = *(const float4*)(s2b + (size_t)(BATCH * NH * SRCLEN) + row + j);
      v.x += v2.x; v.y += v2.y; v.z += v2.z; v.w += v2.w;
      val[t] = v;
      vmax = fmaxf(vmax, fmaxf(fmaxf(v.x, v.y), fmaxf(v.z, v.w)));
    }
#pragma unroll
    for (int o = 1; o <= 8; o <<= 1) vmax = fmaxf(vmax, __shfl_xor(vmax, o, 64));
    float lsum = 0.f;
#pragma unroll
    for (int t = 0; t < 8; ++t){
      val[t].x = __expf(val[t].x - vmax); val[t].y = __expf(val[t].y - vmax);
      val[t].z = __expf(val[t].z - vmax); val[t].w = __expf(val[t].w - vmax);
      lsum += val[t].x + val[t].y + val[t].z + val[t].w;
    }
#pragma unroll
    for (int o = 1; o <= 8; o <<= 1) lsum += __shfl_xor(lsum, o, 64);
    float inv = 1.f / lsum;
#pragma unroll
    for (int t = 0; t < 8; ++t){
      const int j = jp + t * 64;
      pT[j + 0][h] = val[t].x * inv; pT[j + 1][h] = val[t].y * inv;
      pT[j + 2][h] = val[t].z * inv; pT[j + 3][h] = val[t].w * inv;
    }
  }
  __syncthreads();
  const float* ep = enc + (size_t)b * SRCLEN * DIM + c0 + lane;
  const int jb = wave * 128;
  float acc[16];
#pragma unroll
  for (int m = 0; m < 16; ++m) acc[m] = 0.f;
  float cur[8], nxt[8];
#pragma unroll
  for (int i = 0; i < 8; ++i) cur[i] = ep[(size_t)(jb + i) * DIM];
#pragma unroll
  for (int t = 0; t < 16; ++t){
    if (t < 15){
#pragma unroll
      for (int i = 0; i < 8; ++i)
        nxt[i] = ep[(size_t)(jb + (t + 1) * 8 + i) * DIM];
    }
#pragma unroll
    for (int i = 0; i < 8; ++i){
      const int j = jb + t * 8 + i;
      float4 p0 = *(const float4*)(&pT[j][0]);
      float4 p1 = *(const float4*)(&pT[j][4]);
      float4 p2 = *(const float4*)(&pT[j][8]);
      float4 p3 = *(const float4*)(&pT[j][12]);
      float ev = cur[i];
      acc[0] = fmaf(p0.x, ev, acc[0]);  acc[1] = fmaf(p0.y, ev, acc[1]);
      acc[2] = fmaf(p0.z, ev, acc[2]);  acc[3] = fmaf(p0.w, ev, acc[3]);
      acc[4] = fmaf(p1.x, ev, acc[4]);  acc[5] = fmaf(p1.y, ev, acc[5]);
      acc[6] = fmaf(p1.z, ev, acc[6]);  acc[7] = fmaf(p1.w, ev, acc[7]);
      acc[8] = fmaf(p2.x, ev, acc[8]);  acc[9] = fmaf(p2.y, ev, acc[9]);
      acc[10] = fmaf(p2.z, ev, acc[10]); acc[11] = fmaf(p2.w, ev, acc[11]);
      acc[12] = fmaf(p3.x, ev, acc[12]); acc[13] = fmaf(p3.y, ev, acc[13]);
      acc[14] = fmaf(p3.z, ev, acc[14]); acc[15] = fmaf(p3.w, ev, acc[15]);
    }
#pragma unroll
    for (int i = 0; i < 8; ++i) cur[i] = nxt[i];
  }
#pragma unroll
  for (int m = 0; m < 16; ++m) Ps[wave][m][lane] = acc[m];
  __syncthreads();
  const int nl = tid & 63, mg = (tid >> 6) * 4;
#pragma unroll
  for (int mm = 0; mm < 4; ++mm){
    int m = mg + mm;
    float r = Ps[0][m][nl] + Ps[1][m][nl] + Ps[2][m][nl] + Ps[3][m][nl];
    ctx[((size_t)b * NH + m) * DIM + c0 + nl] = r;
  }
}

extern "C" void kernel_launch(void* const* d_in, const int* in_sizes, int n_in,
                              void* d_out, int out_size, void* d_ws, size_t ws_size,
                              hipStream_t stream){
  const float* de   = (const float*)d_in[0];
  const float* enc  = (const float*)d_in[1];
  const float* pk   = (const float*)d_in[2];
  const float* pv   = (const float*)d_in[3];
  const int*   cl   = (const int*)d_in[4];
  const float* pe   = (const float*)d_in[5];
  const float* saqw = (const float*)d_in[6];
  const float* sakw = (const float*)d_in[7];
  const float* savw = (const float*)d_in[8];
  const float* saow = (const float*)d_in[9];
  const float* caqw = (const float*)d_in[10];
  const float* cakw = (const float*)d_in[11];
  const float* cavw = (const float*)d_in[12];
  const float* caow = (const float*)d_in[13];
  const float* saqb = (const float*)d_in[14];
  const float* sakb = (const float*)d_in[15];
  const float* savb = (const float*)d_in[16];
  const float* saob = (const float*)d_in[17];
  const float* caqb = (const float*)d_in[18];
  const float* cakb = (const float*)d_in[19];
  const float* cavb = (const float*)d_in[20];
  const float* caob = (const float*)d_in[21];
  const float* fc1w = (const float*)d_in[22];
  const float* fc1b = (const float*)d_in[23];
  const float* fc2w = (const float*)d_in[24];
  const float* fc2b = (const float*)d_in[25];
  const float* ln1w = (const float*)d_in[26];
  const float* ln2w = (const float*)d_in[27];
  const float* ln3w = (const float*)d_in[28];
  const float* ln1b = (const float*)d_in[29];
  const float* ln2b = (const float*)d_in[30];
  const float* ln3b = (const float*)d_in[31];
  const float* lmw  = (const float*)d_in[32];
  float* out = (float*)d_out;
  float* ws  = (float*)d_ws;

  float* h3buf = ws;               // [16][1024] layer input (ln3 out / embed)
  float* h1buf = ws + 16384;       // [16][1024] post-ln1
  float* h2buf = ws + 32768;       // [16][1024] post-ln2
  float* satt  = ws + 49152;       // [16][1024]
  float* Abuf  = ws + 65536;       // A_o | A_co | A_f2, 3 x [16][1024]
  float* A_o   = Abuf;
  float* A_co  = Abuf + 16384;
  float* A_f2  = Abuf + 32768;
  float* g     = ws + 114688;      // [16][16][1024]
  float* ctx   = ws + 376832;      // [16][16][1024]
  float* Pqkv  = ws + 638976;      // [3][4][16][1024]
  float* Pcq   = ws + 835584;      // [8][16][1024]
  float* Pvo   = ws + 966656;      // [8][16][1024]
  float* Pf1   = ws + 1097728;     // [4][16][4096]
  float* s2b   = ws + 1359872;     // [2][256][512]
  float* Plm   = ws + 1622016;     // [2][16][32000]

  float* out_k = out + 512000;     // [L][16][1024]
  float* out_v = out + 610304;     // [L][16][1024]

  k_embed<<<16, 256, 0, stream>>>(de, pe, cl, h3buf);

  for (int i = 0; i < LYRS; ++i){
    size_t wo = (size_t)i * DIM * DIM;
    size_t bo = (size_t)i * DIM;
    float* ko = out_k + (size_t)i * BD;
    float* vo = out_v + (size_t)i * BD;
    const float* pk_l = pk + (size_t)i * BATCH * NCACHE * DIM;
    const float* pv_l = pv + (size_t)i * BATCH * NCACHE * DIM;
    // ---- QKV (ln3 of previous layer fused for i>=1) ----
    if (i == 0){
      k_gemv_ms3<256><<<dim3(16, 3, 4), 256, 0, stream>>>(h3buf,
          saqw + wo, sakw + wo, savw + wo, Pqkv);
    } else {
      size_t po = (size_t)(i - 1) * DIM;
      k_gemv_ln3<256><<<dim3(16, 3, 4), 256, 0, stream>>>(h2buf, A_f2,
          fc2b + po, ln3w + po, ln3b + po,
          saqw + wo, sakw + wo, savw + wo, h3buf, Pqkv);
    }
    // ---- self-attention (+ zero A_o/A_co/A_f2 for this layer) ----
    k_self_attn<<<256, 512, 0, stream>>>(Pqkv, saqb + bo, sakb + bo, savb + bo,
        pk_l, pv_l, satt, ko, vo, Abuf);
    // ---- O-projection -> atomic A_o ----
    k_gemv_ms<128, 0, false, true><<<dim3(16, 1, 8), 256, 0, stream>>>(satt,
        DIM, 0, 0, nullptr, saow + wo, DIM, 0, A_o, DIM, 0, 0);
    // ---- cross-attn Q projection (ln1 fused; writes h1buf) ----
    k_gemv_ln<128><<<dim3(16, 1, 8), 256, 0, stream>>>(h3buf, A_o, saob + bo,
        ln1w + bo, ln1b + bo, caqw + wo, h1buf, Pcq, DIM, BD);
    // ---- g = qv . kw (K-projection folded into query) ----
    k_gmat2<<<dim3(16, 16), 256, 0, stream>>>(Pcq, caqb + bo, cakw + wo, g);
    // ---- scores ----
    k_gemv_ms<512, 0, false, false><<<dim3(8, 16, 2), 256, 0, stream>>>(g, DIM,
        NH * DIM, 0, nullptr, enc, DIM, SRCLEN * DIM, s2b, SRCLEN, NH * SRCLEN,
        BATCH * NH * SRCLEN);
    // ---- ctx with inline softmax ----
    k_ctx_sm<<<dim3(16, 16), 256, 0, stream>>>(s2b, enc, ctx);
    // ---- V-projection of ctx (per-head) ----
    k_gemv_ms<128, 0, false, false><<<dim3(1, 16, 8), 256, 0, stream>>>(ctx,
        NH * DIM, DIM, 0, nullptr, cavw + wo, DIM, HDIM * DIM, Pvo, DIM, HDIM, BD);
    // ---- cross-attn O-projection (folds Pvo + cavb) -> atomic A_co ----
    k_gemv_ms<128, 8, false, true><<<dim3(16, 1, 8), 256, 0, stream>>>(Pvo,
        DIM, 0, BD, cavb + bo, caow + wo, DIM, 0, A_co, DIM, 0, 0);
    // ---- fc1 (ln2 fused; writes h2buf) ----
    k_gemv_ln<256><<<dim3(64, 1, 4), 256, 0, stream>>>(h1buf, A_co, caob + bo,
        ln2w + bo, ln2b + bo, fc1w + (size_t)i * FFNDIM * DIM, h2buf,
        Pf1, FFNDIM, BF);
    // ---- fc2 (folds Pf1 + fc1b + SiLU) -> atomic A_f2 ----
    k_gemv_ms<256, 4, true, true><<<dim3(16, 1, 16), 256, 0, stream>>>(Pf1,
        FFNDIM, 0, BF, fc1b + (size_t)i * FFNDIM,
        fc2w + (size_t)i * DIM * FFNDIM, FFNDIM, 0, A_f2, DIM, 0, 0);
  }
  // ---- lm_head (ln3 of layer 5 fused) ----
  {
    size_t po = (size_t)(LYRS - 1) * DIM;
    k_gemv_ln<512><<<dim3(500, 1, 2), 256, 0, stream>>>(h2buf, A_f2,
        fc2b + po, ln3w + po, ln3b + po, lmw, nullptr, Plm, VOCAB, BV);
  }
  k_fin2<<<BV / 256, 256, 0, stream>>>(Plm, out);
}